// Round 7
// baseline (1988788.281 us; speedup 1.0000x reference)
//
#include <hip/hip_runtime.h>

#define T_STEPS 512
#define BB 64
#define EE 300
#define EP 320
#define HH 512
#define G3 1536
#define HB (BB*HH)   // halves per h slot
#define RING 4

typedef _Float16 f16x8 __attribute__((ext_vector_type(8)));
typedef float f32x4 __attribute__((ext_vector_type(4)));
typedef int i32x4 __attribute__((ext_vector_type(4)));

__device__ __forceinline__ f32x4 mf(f16x8 a, f16x8 b, f32x4 c) {
  return __builtin_amdgcn_mfma_f32_16x16x32_f16(a, b, c, 0, 0, 0);
}

struct HMat { i32x4 q[16]; };   // 64 VGPRs: one lane's 16 fragments of a 64x512 f16 matrix

// 16 back-to-back XCD-L2 (sc0 = bypass L1, hit L2) 16B loads + FULL drain in ONE
// asm block (in-flight regs must never escape a block — round-4 NaN lesson).
#define LOADS16_W0                                                   \
    "global_load_dwordx4 %0,  %16, %17 sc0\n\t"                      \
    "global_load_dwordx4 %1,  %16, %17 offset:64 sc0\n\t"            \
    "global_load_dwordx4 %2,  %16, %17 offset:128 sc0\n\t"           \
    "global_load_dwordx4 %3,  %16, %17 offset:192 sc0\n\t"           \
    "global_load_dwordx4 %4,  %16, %17 offset:256 sc0\n\t"           \
    "global_load_dwordx4 %5,  %16, %17 offset:320 sc0\n\t"           \
    "global_load_dwordx4 %6,  %16, %17 offset:384 sc0\n\t"           \
    "global_load_dwordx4 %7,  %16, %17 offset:448 sc0\n\t"           \
    "global_load_dwordx4 %8,  %16, %17 offset:512 sc0\n\t"           \
    "global_load_dwordx4 %9,  %16, %17 offset:576 sc0\n\t"           \
    "global_load_dwordx4 %10, %16, %17 offset:640 sc0\n\t"           \
    "global_load_dwordx4 %11, %16, %17 offset:704 sc0\n\t"           \
    "global_load_dwordx4 %12, %16, %17 offset:768 sc0\n\t"           \
    "global_load_dwordx4 %13, %16, %17 offset:832 sc0\n\t"           \
    "global_load_dwordx4 %14, %16, %17 offset:896 sc0\n\t"           \
    "global_load_dwordx4 %15, %16, %17 offset:960 sc0\n\t"           \
    "s_waitcnt vmcnt(0)"

#define HM_OUTS(m) "=v"((m).q[0]), "=v"((m).q[1]), "=v"((m).q[2]), "=v"((m).q[3]),   \
                   "=v"((m).q[4]), "=v"((m).q[5]), "=v"((m).q[6]), "=v"((m).q[7]),   \
                   "=v"((m).q[8]), "=v"((m).q[9]), "=v"((m).q[10]), "=v"((m).q[11]), \
                   "=v"((m).q[12]), "=v"((m).q[13]), "=v"((m).q[14]), "=v"((m).q[15])

__device__ __forceinline__ void load16_l2(HMat& m, const void* base, int voff) {
  asm volatile(LOADS16_W0 : HM_OUTS(m) : "v"(voff), "s"(base) : "memory");
}

// batched x-prefetch: 10 plain cached loads + full drain (x0 is immutable)
__device__ __forceinline__ void loadx10_wait(i32x4* xq, const void* base, int voff) {
  asm volatile(
    "global_load_dwordx4 %0, %10, %11\n\t"
    "global_load_dwordx4 %1, %10, %11 offset:64\n\t"
    "global_load_dwordx4 %2, %10, %11 offset:128\n\t"
    "global_load_dwordx4 %3, %10, %11 offset:192\n\t"
    "global_load_dwordx4 %4, %10, %11 offset:256\n\t"
    "global_load_dwordx4 %5, %10, %11 offset:320\n\t"
    "global_load_dwordx4 %6, %10, %11 offset:384\n\t"
    "global_load_dwordx4 %7, %10, %11 offset:448\n\t"
    "global_load_dwordx4 %8, %10, %11 offset:512\n\t"
    "global_load_dwordx4 %9, %10, %11 offset:576\n\t"
    "s_waitcnt vmcnt(0)"
    : "=v"(xq[0]), "=v"(xq[1]), "=v"(xq[2]), "=v"(xq[3]), "=v"(xq[4]),
      "=v"(xq[5]), "=v"(xq[6]), "=v"(xq[7]), "=v"(xq[8]), "=v"(xq[9])
    : "v"(voff), "s"(base) : "memory");
}

__device__ __forceinline__ f16x8 fragq(i32x4 q) {
  union { i32x4 i; f16x8 v; } x; x.i = q; return x.v;
}

// h-tile publish: 16B store to XCD L2 (write-through L1)
__device__ __forceinline__ void st16_l2(void* p, f16x8 v) {
  i32x4 iv;
  __builtin_memcpy(&iv, &v, 16);
  asm volatile("global_store_dwordx4 %0, %1, off sc0" :: "v"(p), "v"(iv) : "memory");
}

// flag publish: byte store visible in BOTH L2 and MALL (sc0 sc1) so the
// device-scope escalation path can also observe it
__device__ __forceinline__ void st1_flag(char* p, int v) {
  asm volatile("global_store_byte %0, %1, off sc0 sc1" :: "v"(p), "v"(v) : "memory");
}

__device__ __forceinline__ int ld4_sc0(const int* p) {
  int r;
  asm volatile("global_load_dword %0, %1, off sc0\n\ts_waitcnt vmcnt(0)"
               : "=v"(r) : "v"(p) : "memory");
  return r;
}
__device__ __forceinline__ int ld4_dev(const int* p) {
  int r;
  asm volatile("global_load_dword %0, %1, off sc0 sc1\n\ts_waitcnt vmcnt(0)"
               : "=v"(r) : "v"(p) : "memory");
  return r;
}

// wait until all 32 WG-words of f0 (lanes 0-31) and f1 (lanes 32-63) hit 0x01010101.
// sc0 (L2) polls; escalates to device scope after ~30k iters (hang-proofing).
__device__ __forceinline__ void poll2(const int* f0, const int* f1) {
  const int lane = threadIdx.x & 63;
  const int* p = nullptr;
  if (lane < 32) { if (f0) p = f0 + lane; }
  else           { if (f1) p = f1 + (lane - 32); }
  int it = 0;
  for (;;) {
    int ok = 1;
    if (p) ok = ((it < 30000 ? ld4_sc0(p) : ld4_dev(p)) == 0x01010101);
    if (__all(ok)) return;
    __builtin_amdgcn_s_sleep(1);
    ++it;
  }
}

__device__ __forceinline__ float sigf(float x) { return 1.f / (1.f + __expf(-x)); }

struct B3 { f16x8 r, z, n; };
// W row-major [1536][K]; rows g*512 + j (plain cached loads — weights stay hot in L1/L2)
__device__ __forceinline__ B3 ldB(const _Float16* __restrict__ W, int K, int row0, int koff) {
  B3 o;
  const _Float16* p = W + (size_t)row0 * K + koff;
  o.r = *(const f16x8*)p;
  o.z = *(const f16x8*)(p + (size_t)512 * K);
  o.n = *(const f16x8*)(p + (size_t)1024 * K);
  return o;
}

__global__ void prep_x0(const int* __restrict__ texts, const float* __restrict__ emb,
                        _Float16* __restrict__ x0) {
  const size_t N = (size_t)T_STEPS * BB * EP;
  const size_t stride = (size_t)gridDim.x * blockDim.x;
  for (size_t i = (size_t)blockIdx.x * blockDim.x + threadIdx.x; i < N; i += stride) {
    int e = (int)(i % EP);
    size_t tb = i / EP;
    float v = 0.f;
    if (e < EE) v = emb[(size_t)texts[tb] * EE + e];
    x0[i] = (_Float16)v;
  }
}

__global__ void prep_w(const float* __restrict__ Wih0, const float* __restrict__ Whh0,
                       const float* __restrict__ bih0, const float* __restrict__ bhh0,
                       const float* __restrict__ Wih1, const float* __restrict__ Whh1,
                       const float* __restrict__ bih1, const float* __restrict__ bhh1,
                       _Float16* __restrict__ W0x, _Float16* __restrict__ W0h,
                       _Float16* __restrict__ W1x, _Float16* __restrict__ W1h,
                       float* __restrict__ bias0, float* __restrict__ bias1) {
  const size_t stride = (size_t)gridDim.x * blockDim.x;
  const size_t gid = (size_t)blockIdx.x * blockDim.x + threadIdx.x;
  for (size_t i = gid; i < (size_t)G3 * EP; i += stride) {
    int k = (int)(i % EP); int n = (int)(i / EP);
    W0x[i] = (k < EE) ? (_Float16)Wih0[(size_t)n * EE + k] : (_Float16)0.f;
  }
  for (size_t i = gid; i < (size_t)G3 * HH; i += stride) {
    W0h[i] = (_Float16)Whh0[i];
    W1x[i] = (_Float16)Wih1[i];
    W1h[i] = (_Float16)Whh1[i];
  }
  for (size_t i = gid; i < (size_t)HH; i += stride) {
    bias0[i]        = bih0[i] + bhh0[i];
    bias0[512 + i]  = bih0[512 + i] + bhh0[512 + i];
    bias0[1024 + i] = bih0[1024 + i];
    bias0[1536 + i] = bhh0[1024 + i];
    bias1[i]        = bih1[i] + bhh1[i];
    bias1[512 + i]  = bih1[512 + i] + bhh1[512 + i];
    bias1[1024 + i] = bih1[1024 + i];
    bias1[1536 + i] = bhh1[1024 + i];
  }
}

// 768 launched WGs; exactly 64 claim roles, ALL ON ONE PHYSICAL XCD (verified
// via HW_REG_XCC_ID + atomic claim; first XCD to fill 64 slots wins by CAS).
// Role 0..31 = layer0 j-chunks, 32..63 = layer1 j-chunks. All recurrence
// traffic (h tiles, flags, polls) stays inside that XCD's L2 via sc0.
__global__ __launch_bounds__(256, 1) void gru_persistent(
    const _Float16* __restrict__ x0,
    const _Float16* __restrict__ W0x, const _Float16* __restrict__ W0h,
    const _Float16* __restrict__ W1x, const _Float16* __restrict__ W1h,
    const float* __restrict__ bias0, const float* __restrict__ bias1,
    _Float16* h1ring, _Float16* h2buf, float* pooled,
    int* flags0, int* flags1, int* claim, int* winner)
{
  const int tid = threadIdx.x;
  __shared__ int s_role;
  __shared__ _Float16 tile[2][4][16][16];   // [parity][wave][row][col] — wave-private
  __shared__ float accum[T_STEPS][16];      // pooled accumulator (L1 roles)

  if (tid == 0) {
    int xcd;
    asm volatile("s_getreg_b32 %0, hwreg(HW_REG_XCC_ID)" : "=s"(xcd));
    xcd &= 7;
    int idx = __hip_atomic_fetch_add(claim + xcd * 16, 1, __ATOMIC_RELAXED,
                                     __HIP_MEMORY_SCOPE_AGENT);
    int role = -1;
    if (idx < 64) {
      if (idx == 63) {   // this XCD just filled 64 slots -> try to win
        int expected = 0;
        __hip_atomic_compare_exchange_strong(winner, &expected, xcd + 1,
                                             __ATOMIC_RELEASE, __ATOMIC_RELAXED,
                                             __HIP_MEMORY_SCOPE_AGENT);
      }
      int wv;
      while ((wv = __hip_atomic_load(winner, __ATOMIC_RELAXED,
                                     __HIP_MEMORY_SCOPE_AGENT)) == 0)
        __builtin_amdgcn_s_sleep(8);
      if (wv == xcd + 1) role = idx;
    }
    s_role = role;
  }
  __syncthreads();
  const int role = s_role;
  if (role < 0) return;   // not a winner — free the CU

  const int L    = role >> 5;
  const int w    = role & 31;
  const int jb   = w * 16;
  const int bsub = tid >> 6;          // wave index: owns batch rows 16*bsub..+15
  const int lane = tid & 63;
  const int quad = lane >> 4;
  const int l15  = lane & 15;
  const int brow = bsub * 16 + l15;   // A-operand row (batch)
  const int j    = jb + l15;          // output column
  const int koff = quad * 8;
  const int hoff = brow * (HH * 2) + quad * 16;   // byte voffset into an h slot

  for (int i = tid; i < T_STEPS * 16; i += 256) ((float*)accum)[i] = 0.f;
  __syncthreads();

  if (L == 0) {
    const float br = bias0[j], bz = bias0[512 + j];
    const float bnx = bias0[1024 + j], bnh = bias0[1536 + j];
    const int xoff = brow * (EP * 2) + quad * 16;
    i32x4 xq[10];
    loadx10_wait(xq, x0, xoff);       // stage-0 x
    for (int s = 0; s < T_STEPS; ++s) {
      f32x4 aR = {0.f,0.f,0.f,0.f}, aZ = {0.f,0.f,0.f,0.f};
      f32x4 aNX = {0.f,0.f,0.f,0.f}, aNH = {0.f,0.f,0.f,0.f};
      #pragma unroll 5
      for (int c = 0; c < 10; ++c) {   // x-part first (no cross-WG dependency)
        f16x8 a = fragq(xq[c]);
        B3 bb = ldB(W0x, EP, j, c * 32 + koff);
        aR = mf(a, bb.r, aR); aZ = mf(a, bb.z, aZ); aNX = mf(a, bb.n, aNX);
      }
      // need: all h1[s-1] published; ring slot s%RING free (L1 finished s-RING)
      if (s >= 1)
        poll2(flags0 + (size_t)(s - 1) * 32,
              (s >= RING) ? flags1 + (size_t)(s - RING) * 32 : nullptr);
      if (s >= 1) {
        HMat hA;
        load16_l2(hA, h1ring + ((s - 1) & (RING - 1)) * HB, hoff);
        #pragma unroll 4
        for (int c = 0; c < 16; ++c) {
          f16x8 a = fragq(hA.q[c]);
          B3 bb = ldB(W0h, HH, j, c * 32 + koff);
          aR = mf(a, bb.r, aR); aZ = mf(a, bb.z, aZ); aNH = mf(a, bb.n, aNH);
        }
      }

      _Float16 (*tc)[16] = tile[s & 1][bsub];
      _Float16 (*tp)[16] = tile[(s + 1) & 1][bsub];
      #pragma unroll
      for (int rg = 0; rg < 4; ++rg) {
        const int rr = quad * 4 + rg;           // C/D row = quad*4+reg (within wave's 16)
        float r = sigf(aR[rg] + br);
        float z = sigf(aZ[rg] + bz);
        float n = tanhf(aNX[rg] + bnx + r * (aNH[rg] + bnh));
        float hp = (s >= 1) ? (float)tp[rr][l15] : 0.f;
        tc[rr][l15] = (_Float16)((1.f - z) * n + z * hp);
      }
      if (lane < 32) {                          // publish own 16 rows into XCD L2
        const int row = lane >> 1, seg = lane & 1;
        f16x8 v = *(const f16x8*)&tc[row][seg * 8];
        st16_l2(h1ring + (s & (RING - 1)) * HB + (size_t)(bsub * 16 + row) * HH + jb + seg * 8, v);
      }
      __builtin_amdgcn_s_waitcnt(0);            // drain to L2 (release)
      if (lane == 0) st1_flag((char*)(flags0 + (size_t)s * 32 + w) + bsub, 1);
      if (s + 1 < T_STEPS)                      // batched x prefetch
        loadx10_wait(xq, x0 + (size_t)(s + 1) * BB * EP, xoff);
    }
  } else {
    const float br = bias1[j], bz = bias1[512 + j];
    const float bnx = bias1[1024 + j], bnh = bias1[1536 + j];
    for (int t = 0; t < T_STEPS; ++t) {
      f32x4 aR = {0.f,0.f,0.f,0.f}, aZ = {0.f,0.f,0.f,0.f};
      f32x4 aNX = {0.f,0.f,0.f,0.f}, aNH = {0.f,0.f,0.f,0.f};
      // phase 1: self-recurrence (h2[t-1]) while L0 may still be finishing h1[t]
      if (t >= 1) {
        poll2(nullptr, flags1 + (size_t)(t - 1) * 32);
        HMat A2;
        load16_l2(A2, h2buf + ((t - 1) & 1) * HB, hoff);
        #pragma unroll 4
        for (int c = 0; c < 16; ++c) {
          f16x8 a = fragq(A2.q[c]);
          B3 bb = ldB(W1h, HH, j, c * 32 + koff);
          aR = mf(a, bb.r, aR); aZ = mf(a, bb.z, aZ); aNH = mf(a, bb.n, aNH);
        }
      }
      // phase 2: h1[t] from layer 0
      poll2(flags0 + (size_t)t * 32, nullptr);
      {
        HMat A1;
        load16_l2(A1, h1ring + (t & (RING - 1)) * HB, hoff);
        #pragma unroll 4
        for (int c = 0; c < 16; ++c) {
          f16x8 a = fragq(A1.q[c]);
          B3 bb = ldB(W1x, HH, j, c * 32 + koff);
          aR = mf(a, bb.r, aR); aZ = mf(a, bb.z, aZ); aNX = mf(a, bb.n, aNX);
        }
      }

      _Float16 (*tc)[16] = tile[t & 1][bsub];
      _Float16 (*tp)[16] = tile[(t + 1) & 1][bsub];
      #pragma unroll
      for (int rg = 0; rg < 4; ++rg) {
        const int rr = quad * 4 + rg;
        float r = sigf(aR[rg] + br);
        float z = sigf(aZ[rg] + bz);
        float n = tanhf(aNX[rg] + bnx + r * (aNH[rg] + bnh));
        float hp = (t >= 1) ? (float)tp[rr][l15] : 0.f;
        tc[rr][l15] = (_Float16)((1.f - z) * n + z * hp);
      }
      if (lane < 32) {
        const int row = lane >> 1, seg = lane & 1;
        f16x8 v = *(const f16x8*)&tc[row][seg * 8];
        st16_l2(h2buf + (t & 1) * HB + (size_t)(bsub * 16 + row) * HH + jb + seg * 8, v);
      }
      __builtin_amdgcn_s_waitcnt(0);
      if (lane == 0) st1_flag((char*)(flags1 + (size_t)t * 32 + w) + bsub, 1);
      // pooled partial: LDS accumulate (no global atomics in the loop)
      if (lane < 16) {
        float sum = 0.f;
        #pragma unroll
        for (int r = 0; r < 16; ++r) sum += (float)tc[r][lane];
        atomicAdd(&accum[t][lane], sum);
      }
    }
    __syncthreads();
    for (int i = tid; i < T_STEPS * 16; i += 256) {   // write raw batch-sums once
      int t = i >> 4, u = i & 15;
      pooled[(size_t)t * HH + jb + u] = accum[t][u];
    }
  }
}

__global__ void fc_kernel(const float* __restrict__ pooled, const float* __restrict__ fcW,
                          const float* __restrict__ fcb, float* __restrict__ out) {
  const int t = blockIdx.x;
  const int lane = threadIdx.x;  // 64 = one wave
  float a0 = 0.f, a1 = 0.f, a2 = 0.f, a3 = 0.f, a4 = 0.f;
  for (int jj = lane; jj < HH; jj += 64) {
    float p = pooled[(size_t)t * HH + jj];
    a0 += p * fcW[jj];
    a1 += p * fcW[512 + jj];
    a2 += p * fcW[1024 + jj];
    a3 += p * fcW[1536 + jj];
    a4 += p * fcW[2048 + jj];
  }
  #pragma unroll
  for (int off = 32; off > 0; off >>= 1) {
    a0 += __shfl_down(a0, off, 64);
    a1 += __shfl_down(a1, off, 64);
    a2 += __shfl_down(a2, off, 64);
    a3 += __shfl_down(a3, off, 64);
    a4 += __shfl_down(a4, off, 64);
  }
  if (lane == 0) {
    const float sc = 1.f / 64.f;
    out[t * 5 + 0] = a0 * sc + fcb[0];
    out[t * 5 + 1] = a1 * sc + fcb[1];
    out[t * 5 + 2] = a2 * sc + fcb[2];
    out[t * 5 + 3] = a3 * sc + fcb[3];
    out[t * 5 + 4] = a4 * sc + fcb[4];
  }
}

extern "C" void kernel_launch(void* const* d_in, const int* in_sizes, int n_in,
                              void* d_out, int out_size, void* d_ws, size_t ws_size,
                              hipStream_t stream) {
  const int*   texts = (const int*)  d_in[0];
  const float* emb   = (const float*)d_in[1];
  const float* Wih0  = (const float*)d_in[2];
  const float* Whh0  = (const float*)d_in[3];
  const float* bih0  = (const float*)d_in[4];
  const float* bhh0  = (const float*)d_in[5];
  const float* Wih1  = (const float*)d_in[6];
  const float* Whh1  = (const float*)d_in[7];
  const float* bih1  = (const float*)d_in[8];
  const float* bhh1  = (const float*)d_in[9];
  const float* fcW   = (const float*)d_in[10];
  const float* fcb   = (const float*)d_in[11];
  float* out = (float*)d_out;

  char* ws = (char*)d_ws;
  int*      claim  = (int*)ws;                        // 8 XCD counters, 64B apart
  int*      winner = (int*)(ws + 2048);               // 0 = undecided, else xcd+1
  int*      flags0 = (int*)(ws + 4096);               // 65536 B [512][32] int
  int*      flags1 = (int*)(ws + 69632);              // 65536 B
  float*    pooled = (float*)(ws + 135168);           // 1048576 B [512][512] f32
  _Float16* h1ring = (_Float16*)(ws + 1183744);       // 262144 B (4 x 64x512 f16)
  _Float16* h2buf  = (_Float16*)(ws + 1445888);       // 131072 B (2 slots)
  _Float16* x0     = (_Float16*)(ws + 1576960);       // 20971520 B [512][64][320]
  _Float16* W0x    = (_Float16*)(ws + 22548480);      // 983040 B  [1536][320]
  _Float16* W0h    = (_Float16*)(ws + 23531520);      // 1572864 B [1536][512]
  _Float16* W1x    = (_Float16*)(ws + 25104384);      // 1572864 B
  _Float16* W1h    = (_Float16*)(ws + 26677248);      // 1572864 B
  float*    bias0  = (float*)(ws + 28250112);         // 8192 B (r,z,nx,nh)
  float*    bias1  = (float*)(ws + 28258304);         // 8192 B
  // total ws use: 28266496 B

  hipMemsetAsync(ws, 0, 135168, stream);  // claim + winner + flags = zeros
  prep_x0<<<4096, 256, 0, stream>>>(texts, emb, x0);
  prep_w<<<1024, 256, 0, stream>>>(Wih0, Whh0, bih0, bhh0, Wih1, Whh1, bih1, bhh1,
                                   W0x, W0h, W1x, W1h, bias0, bias1);
  gru_persistent<<<768, 256, 0, stream>>>(x0, W0x, W0h, W1x, W1h, bias0, bias1,
                                          h1ring, h2buf, pooled, flags0, flags1,
                                          claim, winner);
  fc_kernel<<<512, 64, 0, stream>>>(pooled, fcW, fcb, out);
}

// Round 8
// 210049.341 us; speedup vs baseline: 9.4682x; 9.4682x over previous
//
#include <hip/hip_runtime.h>

#define T_STEPS 512
#define BB 64
#define EE 300
#define EP 320
#define HH 512
#define G3 1536
#define HB (BB*HH)   // halves per h slot
#define RING 4

typedef _Float16 f16x8 __attribute__((ext_vector_type(8)));
typedef float f32x4 __attribute__((ext_vector_type(4)));
typedef int i32x4 __attribute__((ext_vector_type(4)));

__device__ __forceinline__ f32x4 mf(f16x8 a, f16x8 b, f32x4 c) {
  return __builtin_amdgcn_mfma_f32_16x16x32_f16(a, b, c, 0, 0, 0);
}

struct HMat { i32x4 q[16]; };   // 64 VGPRs: one lane's 16 fragments of a 64x512 f16 matrix

// 16 back-to-back XCD-L2 (sc0 = bypass L1, hit shared L2) 16B loads + FULL drain
// in ONE asm block (in-flight regs must never escape a block — round-4 lesson).
#define LOADS16_W0                                                   \
    "global_load_dwordx4 %0,  %16, %17 sc0\n\t"                      \
    "global_load_dwordx4 %1,  %16, %17 offset:64 sc0\n\t"            \
    "global_load_dwordx4 %2,  %16, %17 offset:128 sc0\n\t"           \
    "global_load_dwordx4 %3,  %16, %17 offset:192 sc0\n\t"           \
    "global_load_dwordx4 %4,  %16, %17 offset:256 sc0\n\t"           \
    "global_load_dwordx4 %5,  %16, %17 offset:320 sc0\n\t"           \
    "global_load_dwordx4 %6,  %16, %17 offset:384 sc0\n\t"           \
    "global_load_dwordx4 %7,  %16, %17 offset:448 sc0\n\t"           \
    "global_load_dwordx4 %8,  %16, %17 offset:512 sc0\n\t"           \
    "global_load_dwordx4 %9,  %16, %17 offset:576 sc0\n\t"           \
    "global_load_dwordx4 %10, %16, %17 offset:640 sc0\n\t"           \
    "global_load_dwordx4 %11, %16, %17 offset:704 sc0\n\t"           \
    "global_load_dwordx4 %12, %16, %17 offset:768 sc0\n\t"           \
    "global_load_dwordx4 %13, %16, %17 offset:832 sc0\n\t"           \
    "global_load_dwordx4 %14, %16, %17 offset:896 sc0\n\t"           \
    "global_load_dwordx4 %15, %16, %17 offset:960 sc0\n\t"           \
    "s_waitcnt vmcnt(0)"

#define HM_OUTS(m) "=v"((m).q[0]), "=v"((m).q[1]), "=v"((m).q[2]), "=v"((m).q[3]),   \
                   "=v"((m).q[4]), "=v"((m).q[5]), "=v"((m).q[6]), "=v"((m).q[7]),   \
                   "=v"((m).q[8]), "=v"((m).q[9]), "=v"((m).q[10]), "=v"((m).q[11]), \
                   "=v"((m).q[12]), "=v"((m).q[13]), "=v"((m).q[14]), "=v"((m).q[15])

__device__ __forceinline__ void load16_l2(HMat& m, const void* base, int voff) {
  asm volatile(LOADS16_W0 : HM_OUTS(m) : "v"(voff), "s"(base) : "memory");
}

// batched x-prefetch: 10 plain cached loads + full drain (x0 is immutable)
__device__ __forceinline__ void loadx10_wait(i32x4* xq, const void* base, int voff) {
  asm volatile(
    "global_load_dwordx4 %0, %10, %11\n\t"
    "global_load_dwordx4 %1, %10, %11 offset:64\n\t"
    "global_load_dwordx4 %2, %10, %11 offset:128\n\t"
    "global_load_dwordx4 %3, %10, %11 offset:192\n\t"
    "global_load_dwordx4 %4, %10, %11 offset:256\n\t"
    "global_load_dwordx4 %5, %10, %11 offset:320\n\t"
    "global_load_dwordx4 %6, %10, %11 offset:384\n\t"
    "global_load_dwordx4 %7, %10, %11 offset:448\n\t"
    "global_load_dwordx4 %8, %10, %11 offset:512\n\t"
    "global_load_dwordx4 %9, %10, %11 offset:576\n\t"
    "s_waitcnt vmcnt(0)"
    : "=v"(xq[0]), "=v"(xq[1]), "=v"(xq[2]), "=v"(xq[3]), "=v"(xq[4]),
      "=v"(xq[5]), "=v"(xq[6]), "=v"(xq[7]), "=v"(xq[8]), "=v"(xq[9])
    : "v"(voff), "s"(base) : "memory");
}

__device__ __forceinline__ f16x8 fragq(i32x4 q) {
  union { i32x4 i; f16x8 v; } x; x.i = q; return x.v;
}

// h-tile publish: 16B store updating the shared XCD L2
__device__ __forceinline__ void st16_l2(void* p, f16x8 v) {
  i32x4 iv;
  __builtin_memcpy(&iv, &v, 16);
  asm volatile("global_store_dwordx4 %0, %1, off sc0" :: "v"(p), "v"(iv) : "memory");
}

// flag publish: sc0-ONLY byte store — must UPDATE the XCD L2 line consumers
// poll. (Round-7 bug: adding sc1 bypassed L2 -> consumers saw stale clean
// line forever -> 3 ms/handoff via the escalation path.)
__device__ __forceinline__ void st1_flag(char* p, int v) {
  asm volatile("global_store_byte %0, %1, off sc0" :: "v"(p), "v"(v) : "memory");
}

__device__ __forceinline__ int ld4_sc0(const int* p) {
  int r;
  asm volatile("global_load_dword %0, %1, off sc0\n\ts_waitcnt vmcnt(0)"
               : "=v"(r) : "v"(p) : "memory");
  return r;
}
__device__ __forceinline__ int ld4_dev(const int* p) {
  int r;
  asm volatile("global_load_dword %0, %1, off sc0 sc1\n\ts_waitcnt vmcnt(0)"
               : "=v"(r) : "v"(p) : "memory");
  return r;
}

// WG-level wait: ONLY wave 0 polls (lanes 0-31: f0 words, 32-63: f1 words),
// then __syncthreads releases the other waves. sc0 polls hit the shared L2;
// every 4096th iter OR-in a device-scope read (bytes only go 0->1, OR safe)
// as a no-deadlock fallback that cannot mask the fast path.
__device__ __forceinline__ void wg_wait(const int* f0, const int* f1) {
  if ((threadIdx.x >> 6) == 0) {
    const int lane = threadIdx.x & 63;
    const int* p = nullptr;
    if (lane < 32) { if (f0) p = f0 + lane; }
    else           { if (f1) p = f1 + (lane - 32); }
    int it = 0;
    for (;;) {
      int ok = 1;
      if (p) {
        int v = ld4_sc0(p);
        if ((it & 4095) == 4095) v |= ld4_dev(p);
        ok = (v == 0x01010101);
      }
      if (__all(ok)) break;
      ++it;
    }
  }
  __syncthreads();
}

__device__ __forceinline__ float sigf(float x) { return 1.f / (1.f + __expf(-x)); }

struct B3 { f16x8 r, z, n; };
// W row-major [1536][K]; rows g*512 + j (plain cached loads — weights stay hot in L1/L2)
__device__ __forceinline__ B3 ldB(const _Float16* __restrict__ W, int K, int row0, int koff) {
  B3 o;
  const _Float16* p = W + (size_t)row0 * K + koff;
  o.r = *(const f16x8*)p;
  o.z = *(const f16x8*)(p + (size_t)512 * K);
  o.n = *(const f16x8*)(p + (size_t)1024 * K);
  return o;
}

__global__ void prep_x0(const int* __restrict__ texts, const float* __restrict__ emb,
                        _Float16* __restrict__ x0) {
  const size_t N = (size_t)T_STEPS * BB * EP;
  const size_t stride = (size_t)gridDim.x * blockDim.x;
  for (size_t i = (size_t)blockIdx.x * blockDim.x + threadIdx.x; i < N; i += stride) {
    int e = (int)(i % EP);
    size_t tb = i / EP;
    float v = 0.f;
    if (e < EE) v = emb[(size_t)texts[tb] * EE + e];
    x0[i] = (_Float16)v;
  }
}

__global__ void prep_w(const float* __restrict__ Wih0, const float* __restrict__ Whh0,
                       const float* __restrict__ bih0, const float* __restrict__ bhh0,
                       const float* __restrict__ Wih1, const float* __restrict__ Whh1,
                       const float* __restrict__ bih1, const float* __restrict__ bhh1,
                       _Float16* __restrict__ W0x, _Float16* __restrict__ W0h,
                       _Float16* __restrict__ W1x, _Float16* __restrict__ W1h,
                       float* __restrict__ bias0, float* __restrict__ bias1) {
  const size_t stride = (size_t)gridDim.x * blockDim.x;
  const size_t gid = (size_t)blockIdx.x * blockDim.x + threadIdx.x;
  for (size_t i = gid; i < (size_t)G3 * EP; i += stride) {
    int k = (int)(i % EP); int n = (int)(i / EP);
    W0x[i] = (k < EE) ? (_Float16)Wih0[(size_t)n * EE + k] : (_Float16)0.f;
  }
  for (size_t i = gid; i < (size_t)G3 * HH; i += stride) {
    W0h[i] = (_Float16)Whh0[i];
    W1x[i] = (_Float16)Wih1[i];
    W1h[i] = (_Float16)Whh1[i];
  }
  for (size_t i = gid; i < (size_t)HH; i += stride) {
    bias0[i]        = bih0[i] + bhh0[i];
    bias0[512 + i]  = bih0[512 + i] + bhh0[512 + i];
    bias0[1024 + i] = bih0[1024 + i];
    bias0[1536 + i] = bhh0[1024 + i];
    bias1[i]        = bih1[i] + bhh1[i];
    bias1[512 + i]  = bih1[512 + i] + bhh1[512 + i];
    bias1[1024 + i] = bih1[1024 + i];
    bias1[1536 + i] = bhh1[1024 + i];
  }
}

// 768 launched WGs; exactly 64 claim roles, ALL ON ONE PHYSICAL XCD (verified
// via HW_REG_XCC_ID + atomic claim; first XCD to fill 64 slots wins by CAS).
// Role 0..31 = layer0 j-chunks, 32..63 = layer1. All recurrence traffic
// (h tiles, flags, polls) stays inside that XCD's shared L2 via sc0.
__global__ __launch_bounds__(256, 1) void gru_persistent(
    const _Float16* __restrict__ x0,
    const _Float16* __restrict__ W0x, const _Float16* __restrict__ W0h,
    const _Float16* __restrict__ W1x, const _Float16* __restrict__ W1h,
    const float* __restrict__ bias0, const float* __restrict__ bias1,
    _Float16* h1ring, _Float16* h2buf, float* pooled,
    int* flags0, int* flags1, int* claim, int* winner)
{
  const int tid = threadIdx.x;
  __shared__ int s_role;
  __shared__ _Float16 tile[2][4][16][16];   // [parity][wave][row][col] — wave-private
  __shared__ float accum[T_STEPS][16];      // pooled accumulator (L1 roles)

  if (tid == 0) {
    int xcd;
    asm volatile("s_getreg_b32 %0, hwreg(HW_REG_XCC_ID)" : "=s"(xcd));
    xcd &= 7;
    int idx = __hip_atomic_fetch_add(claim + xcd * 16, 1, __ATOMIC_RELAXED,
                                     __HIP_MEMORY_SCOPE_AGENT);
    int role = -1;
    if (idx < 64) {
      if (idx == 63) {   // this XCD just filled 64 slots -> try to win
        int expected = 0;
        __hip_atomic_compare_exchange_strong(winner, &expected, xcd + 1,
                                             __ATOMIC_RELEASE, __ATOMIC_RELAXED,
                                             __HIP_MEMORY_SCOPE_AGENT);
      }
      int wv;
      while ((wv = __hip_atomic_load(winner, __ATOMIC_RELAXED,
                                     __HIP_MEMORY_SCOPE_AGENT)) == 0)
        __builtin_amdgcn_s_sleep(8);
      if (wv == xcd + 1) role = idx;
    }
    s_role = role;
  }
  __syncthreads();
  const int role = s_role;
  if (role < 0) return;   // not a winner — free the CU

  const int L    = role >> 5;
  const int w    = role & 31;
  const int jb   = w * 16;
  const int bsub = tid >> 6;          // wave index: owns batch rows 16*bsub..+15
  const int lane = tid & 63;
  const int quad = lane >> 4;
  const int l15  = lane & 15;
  const int brow = bsub * 16 + l15;   // A-operand row (batch)
  const int j    = jb + l15;          // output column
  const int koff = quad * 8;
  const int hoff = brow * (HH * 2) + quad * 16;   // byte voffset into an h slot

  for (int i = tid; i < T_STEPS * 16; i += 256) ((float*)accum)[i] = 0.f;
  __syncthreads();

  if (L == 0) {
    const float br = bias0[j], bz = bias0[512 + j];
    const float bnx = bias0[1024 + j], bnh = bias0[1536 + j];
    const int xoff = brow * (EP * 2) + quad * 16;
    i32x4 xq[10];
    loadx10_wait(xq, x0, xoff);       // stage-0 x
    for (int s = 0; s < T_STEPS; ++s) {
      f32x4 aR = {0.f,0.f,0.f,0.f}, aZ = {0.f,0.f,0.f,0.f};
      f32x4 aNX = {0.f,0.f,0.f,0.f}, aNH = {0.f,0.f,0.f,0.f};
      #pragma unroll 5
      for (int c = 0; c < 10; ++c) {   // x-part first (no cross-WG dependency)
        f16x8 a = fragq(xq[c]);
        B3 bb = ldB(W0x, EP, j, c * 32 + koff);
        aR = mf(a, bb.r, aR); aZ = mf(a, bb.z, aZ); aNX = mf(a, bb.n, aNX);
      }
      // need: all h1[s-1] published; ring slot s%RING free (L1 finished s-RING)
      wg_wait((s >= 1) ? flags0 + (size_t)(s - 1) * 32 : nullptr,
              (s >= RING) ? flags1 + (size_t)(s - RING) * 32 : nullptr);
      if (s >= 1) {
        HMat hA;
        load16_l2(hA, h1ring + ((s - 1) & (RING - 1)) * HB, hoff);
        #pragma unroll 4
        for (int c = 0; c < 16; ++c) {
          f16x8 a = fragq(hA.q[c]);
          B3 bb = ldB(W0h, HH, j, c * 32 + koff);
          aR = mf(a, bb.r, aR); aZ = mf(a, bb.z, aZ); aNH = mf(a, bb.n, aNH);
        }
      }

      _Float16 (*tc)[16] = tile[s & 1][bsub];
      _Float16 (*tp)[16] = tile[(s + 1) & 1][bsub];
      #pragma unroll
      for (int rg = 0; rg < 4; ++rg) {
        const int rr = quad * 4 + rg;           // C/D row = quad*4+reg (within wave's 16)
        float r = sigf(aR[rg] + br);
        float z = sigf(aZ[rg] + bz);
        float n = tanhf(aNX[rg] + bnx + r * (aNH[rg] + bnh));
        float hp = (s >= 1) ? (float)tp[rr][l15] : 0.f;
        tc[rr][l15] = (_Float16)((1.f - z) * n + z * hp);
      }
      if (lane < 32) {                          // publish own 16 rows into XCD L2
        const int row = lane >> 1, seg = lane & 1;
        f16x8 v = *(const f16x8*)&tc[row][seg * 8];
        st16_l2(h1ring + (s & (RING - 1)) * HB + (size_t)(bsub * 16 + row) * HH + jb + seg * 8, v);
      }
      __builtin_amdgcn_s_waitcnt(0);            // drain to L2 (release)
      if (lane == 0) st1_flag((char*)(flags0 + (size_t)s * 32 + w) + bsub, 1);
      if (s + 1 < T_STEPS)                      // batched x prefetch
        loadx10_wait(xq, x0 + (size_t)(s + 1) * BB * EP, xoff);
    }
  } else {
    const float br = bias1[j], bz = bias1[512 + j];
    const float bnx = bias1[1024 + j], bnh = bias1[1536 + j];
    for (int t = 0; t < T_STEPS; ++t) {
      f32x4 aR = {0.f,0.f,0.f,0.f}, aZ = {0.f,0.f,0.f,0.f};
      f32x4 aNX = {0.f,0.f,0.f,0.f}, aNH = {0.f,0.f,0.f,0.f};
      // phase 1: self-recurrence (h2[t-1]) while L0 may still be finishing h1[t]
      wg_wait(nullptr, (t >= 1) ? flags1 + (size_t)(t - 1) * 32 : nullptr);
      if (t >= 1) {
        HMat A2;
        load16_l2(A2, h2buf + ((t - 1) & 1) * HB, hoff);
        #pragma unroll 4
        for (int c = 0; c < 16; ++c) {
          f16x8 a = fragq(A2.q[c]);
          B3 bb = ldB(W1h, HH, j, c * 32 + koff);
          aR = mf(a, bb.r, aR); aZ = mf(a, bb.z, aZ); aNH = mf(a, bb.n, aNH);
        }
      }
      // phase 2: h1[t] from layer 0
      wg_wait(flags0 + (size_t)t * 32, nullptr);
      {
        HMat A1;
        load16_l2(A1, h1ring + (t & (RING - 1)) * HB, hoff);
        #pragma unroll 4
        for (int c = 0; c < 16; ++c) {
          f16x8 a = fragq(A1.q[c]);
          B3 bb = ldB(W1x, HH, j, c * 32 + koff);
          aR = mf(a, bb.r, aR); aZ = mf(a, bb.z, aZ); aNX = mf(a, bb.n, aNX);
        }
      }

      _Float16 (*tc)[16] = tile[t & 1][bsub];
      _Float16 (*tp)[16] = tile[(t + 1) & 1][bsub];
      #pragma unroll
      for (int rg = 0; rg < 4; ++rg) {
        const int rr = quad * 4 + rg;
        float r = sigf(aR[rg] + br);
        float z = sigf(aZ[rg] + bz);
        float n = tanhf(aNX[rg] + bnx + r * (aNH[rg] + bnh));
        float hp = (t >= 1) ? (float)tp[rr][l15] : 0.f;
        tc[rr][l15] = (_Float16)((1.f - z) * n + z * hp);
      }
      if (lane < 32) {
        const int row = lane >> 1, seg = lane & 1;
        f16x8 v = *(const f16x8*)&tc[row][seg * 8];
        st16_l2(h2buf + (t & 1) * HB + (size_t)(bsub * 16 + row) * HH + jb + seg * 8, v);
      }
      __builtin_amdgcn_s_waitcnt(0);
      if (lane == 0) st1_flag((char*)(flags1 + (size_t)t * 32 + w) + bsub, 1);
      // pooled partial: LDS accumulate (no global atomics in the loop)
      if (lane < 16) {
        float sum = 0.f;
        #pragma unroll
        for (int r = 0; r < 16; ++r) sum += (float)tc[r][lane];
        atomicAdd(&accum[t][lane], sum);
      }
    }
    __syncthreads();
    for (int i = tid; i < T_STEPS * 16; i += 256) {   // write raw batch-sums once
      int t = i >> 4, u = i & 15;
      pooled[(size_t)t * HH + jb + u] = accum[t][u];
    }
  }
}

__global__ void fc_kernel(const float* __restrict__ pooled, const float* __restrict__ fcW,
                          const float* __restrict__ fcb, float* __restrict__ out) {
  const int t = blockIdx.x;
  const int lane = threadIdx.x;  // 64 = one wave
  float a0 = 0.f, a1 = 0.f, a2 = 0.f, a3 = 0.f, a4 = 0.f;
  for (int jj = lane; jj < HH; jj += 64) {
    float p = pooled[(size_t)t * HH + jj];
    a0 += p * fcW[jj];
    a1 += p * fcW[512 + jj];
    a2 += p * fcW[1024 + jj];
    a3 += p * fcW[1536 + jj];
    a4 += p * fcW[2048 + jj];
  }
  #pragma unroll
  for (int off = 32; off > 0; off >>= 1) {
    a0 += __shfl_down(a0, off, 64);
    a1 += __shfl_down(a1, off, 64);
    a2 += __shfl_down(a2, off, 64);
    a3 += __shfl_down(a3, off, 64);
    a4 += __shfl_down(a4, off, 64);
  }
  if (lane == 0) {
    const float sc = 1.f / 64.f;
    out[t * 5 + 0] = a0 * sc + fcb[0];
    out[t * 5 + 1] = a1 * sc + fcb[1];
    out[t * 5 + 2] = a2 * sc + fcb[2];
    out[t * 5 + 3] = a3 * sc + fcb[3];
    out[t * 5 + 4] = a4 * sc + fcb[4];
  }
}

extern "C" void kernel_launch(void* const* d_in, const int* in_sizes, int n_in,
                              void* d_out, int out_size, void* d_ws, size_t ws_size,
                              hipStream_t stream) {
  const int*   texts = (const int*)  d_in[0];
  const float* emb   = (const float*)d_in[1];
  const float* Wih0  = (const float*)d_in[2];
  const float* Whh0  = (const float*)d_in[3];
  const float* bih0  = (const float*)d_in[4];
  const float* bhh0  = (const float*)d_in[5];
  const float* Wih1  = (const float*)d_in[6];
  const float* Whh1  = (const float*)d_in[7];
  const float* bih1  = (const float*)d_in[8];
  const float* bhh1  = (const float*)d_in[9];
  const float* fcW   = (const float*)d_in[10];
  const float* fcb   = (const float*)d_in[11];
  float* out = (float*)d_out;

  char* ws = (char*)d_ws;
  int*      claim  = (int*)ws;                        // 8 XCD counters, 64B apart
  int*      winner = (int*)(ws + 2048);               // 0 = undecided, else xcd+1
  int*      flags0 = (int*)(ws + 4096);               // 65536 B [512][32] int
  int*      flags1 = (int*)(ws + 69632);              // 65536 B
  float*    pooled = (float*)(ws + 135168);           // 1048576 B [512][512] f32
  _Float16* h1ring = (_Float16*)(ws + 1183744);       // 262144 B (4 x 64x512 f16)
  _Float16* h2buf  = (_Float16*)(ws + 1445888);       // 131072 B (2 slots)
  _Float16* x0     = (_Float16*)(ws + 1576960);       // 20971520 B [512][64][320]
  _Float16* W0x    = (_Float16*)(ws + 22548480);      // 983040 B  [1536][320]
  _Float16* W0h    = (_Float16*)(ws + 23531520);      // 1572864 B [1536][512]
  _Float16* W1x    = (_Float16*)(ws + 25104384);      // 1572864 B
  _Float16* W1h    = (_Float16*)(ws + 26677248);      // 1572864 B
  float*    bias0  = (float*)(ws + 28250112);         // 8192 B (r,z,nx,nh)
  float*    bias1  = (float*)(ws + 28258304);         // 8192 B
  // total ws use: 28266496 B

  hipMemsetAsync(ws, 0, 135168, stream);  // claim + winner + flags = zeros
  prep_x0<<<4096, 256, 0, stream>>>(texts, emb, x0);
  prep_w<<<1024, 256, 0, stream>>>(Wih0, Whh0, bih0, bhh0, Wih1, Whh1, bih1, bhh1,
                                   W0x, W0h, W1x, W1h, bias0, bias1);
  gru_persistent<<<768, 256, 0, stream>>>(x0, W0x, W0h, W1x, W1h, bias0, bias1,
                                          h1ring, h2buf, pooled, flags0, flags1,
                                          claim, winner);
  fc_kernel<<<512, 64, 0, stream>>>(pooled, fcW, fcb, out);
}

// Round 9
// 22132.858 us; speedup vs baseline: 89.8568x; 9.4904x over previous
//
#include <hip/hip_runtime.h>

#define T_STEPS 512
#define BB 64
#define EE 300
#define EP 320
#define HH 512
#define G3 1536
#define HB (BB*HH)   // halves per h slot
#define RING 4

typedef _Float16 f16x8 __attribute__((ext_vector_type(8)));
typedef float f32x4 __attribute__((ext_vector_type(4)));
typedef int i32x4 __attribute__((ext_vector_type(4)));

__device__ __forceinline__ f32x4 mf(f16x8 a, f16x8 b, f32x4 c) {
  return __builtin_amdgcn_mfma_f32_16x16x32_f16(a, b, c, 0, 0, 0);
}

struct HMat { i32x4 q[16]; };   // 64 VGPRs: one lane's 16 fragments of a 64x512 f16 matrix

// 16 back-to-back MALL (sc1 = device-coherent, bypass L1+L2) 16B loads + FULL
// drain in ONE asm block (in-flight regs never escape a block — round-4 lesson).
// This is the rounds-2..6 PROVEN h-data path.
#define LOADS16_MALL                                                 \
    "global_load_dwordx4 %0,  %16, %17 sc1\n\t"                      \
    "global_load_dwordx4 %1,  %16, %17 offset:64 sc1\n\t"            \
    "global_load_dwordx4 %2,  %16, %17 offset:128 sc1\n\t"           \
    "global_load_dwordx4 %3,  %16, %17 offset:192 sc1\n\t"           \
    "global_load_dwordx4 %4,  %16, %17 offset:256 sc1\n\t"           \
    "global_load_dwordx4 %5,  %16, %17 offset:320 sc1\n\t"           \
    "global_load_dwordx4 %6,  %16, %17 offset:384 sc1\n\t"           \
    "global_load_dwordx4 %7,  %16, %17 offset:448 sc1\n\t"           \
    "global_load_dwordx4 %8,  %16, %17 offset:512 sc1\n\t"           \
    "global_load_dwordx4 %9,  %16, %17 offset:576 sc1\n\t"           \
    "global_load_dwordx4 %10, %16, %17 offset:640 sc1\n\t"           \
    "global_load_dwordx4 %11, %16, %17 offset:704 sc1\n\t"           \
    "global_load_dwordx4 %12, %16, %17 offset:768 sc1\n\t"           \
    "global_load_dwordx4 %13, %16, %17 offset:832 sc1\n\t"           \
    "global_load_dwordx4 %14, %16, %17 offset:896 sc1\n\t"           \
    "global_load_dwordx4 %15, %16, %17 offset:960 sc1\n\t"           \
    "s_waitcnt vmcnt(0)"

#define HM_OUTS(m) "=v"((m).q[0]), "=v"((m).q[1]), "=v"((m).q[2]), "=v"((m).q[3]),   \
                   "=v"((m).q[4]), "=v"((m).q[5]), "=v"((m).q[6]), "=v"((m).q[7]),   \
                   "=v"((m).q[8]), "=v"((m).q[9]), "=v"((m).q[10]), "=v"((m).q[11]), \
                   "=v"((m).q[12]), "=v"((m).q[13]), "=v"((m).q[14]), "=v"((m).q[15])

__device__ __forceinline__ void load16_mall(HMat& m, const void* base, int voff) {
  asm volatile(LOADS16_MALL : HM_OUTS(m) : "v"(voff), "s"(base) : "memory");
}

// batched x-prefetch: 10 plain cached loads + full drain (x0 is immutable)
__device__ __forceinline__ void loadx10_wait(i32x4* xq, const void* base, int voff) {
  asm volatile(
    "global_load_dwordx4 %0, %10, %11\n\t"
    "global_load_dwordx4 %1, %10, %11 offset:64\n\t"
    "global_load_dwordx4 %2, %10, %11 offset:128\n\t"
    "global_load_dwordx4 %3, %10, %11 offset:192\n\t"
    "global_load_dwordx4 %4, %10, %11 offset:256\n\t"
    "global_load_dwordx4 %5, %10, %11 offset:320\n\t"
    "global_load_dwordx4 %6, %10, %11 offset:384\n\t"
    "global_load_dwordx4 %7, %10, %11 offset:448\n\t"
    "global_load_dwordx4 %8, %10, %11 offset:512\n\t"
    "global_load_dwordx4 %9, %10, %11 offset:576\n\t"
    "s_waitcnt vmcnt(0)"
    : "=v"(xq[0]), "=v"(xq[1]), "=v"(xq[2]), "=v"(xq[3]), "=v"(xq[4]),
      "=v"(xq[5]), "=v"(xq[6]), "=v"(xq[7]), "=v"(xq[8]), "=v"(xq[9])
    : "v"(voff), "s"(base) : "memory");
}

__device__ __forceinline__ f16x8 fragq(i32x4 q) {
  union { i32x4 i; f16x8 v; } x; x.i = q; return x.v;
}

// h-tile publish to MALL (proven rounds 2-6 pair with sc1 loads)
__device__ __forceinline__ void st16_mall(void* p, f16x8 v) {
  i32x4 iv;
  __builtin_memcpy(&iv, &v, 16);
  asm volatile("global_store_dwordx4 %0, %1, off sc0 sc1" :: "v"(p), "v"(iv) : "memory");
}

// flag publish, L2 copy: sc0 byte store — L1 is write-through, so this UPDATES
// the producer XCD's shared L2 (consumers on the same XCD poll it via nt).
__device__ __forceinline__ void st1_l2(char* p, int v) {
  asm volatile("global_store_byte %0, %1, off sc0" :: "v"(p), "v"(v) : "memory");
}
// flag publish, device copy (MALL): proven r5 pair with sc1 reads
__device__ __forceinline__ void st1_dev(char* p, int v) {
  asm volatile("global_store_byte %0, %1, off sc0 sc1" :: "v"(p), "v"(v) : "memory");
}

// poll, fast path: nt = no L1 allocate -> every poll misses L1 and reads the
// shared XCD L2 (round-8 bug was sc0 polls hitting the poller's own stale L1)
__device__ __forceinline__ int ld4_nt(const int* p) {
  int r;
  asm volatile("global_load_dword %0, %1, off sc0 nt\n\ts_waitcnt vmcnt(0)"
               : "=v"(r) : "v"(p) : "memory");
  return r;
}
// poll, device path (MALL)
__device__ __forceinline__ int ld4_dev(const int* p) {
  int r;
  asm volatile("global_load_dword %0, %1, off sc1\n\ts_waitcnt vmcnt(0)"
               : "=v"(r) : "v"(p) : "memory");
  return r;
}

// WG-level wait: only wave 0 polls, then __syncthreads releases the others.
// Lanes 0-31 poll edge A, lanes 32-63 edge B (parallel, no extra serial cost).
// An edge exists iff its DEV pointer is set; the L2 pointer (same-XCD producer)
// accelerates it. Dev copy is OR-ed in every 4th iter (flags are monotone 0->1,
// so OR is safe) — bounded worst case even if nt semantics disappoint.
__device__ __forceinline__ void wg_wait(const int* a2, const int* ad,
                                        const int* b2, const int* bd) {
  if ((threadIdx.x >> 6) == 0) {
    const int lane = threadIdx.x & 63;
    const int* p2 = nullptr; const int* pd = nullptr;
    if (lane < 32) { if (ad) { p2 = a2 ? a2 + lane        : nullptr; pd = ad + lane; } }
    else           { if (bd) { p2 = b2 ? b2 + (lane - 32) : nullptr; pd = bd + (lane - 32); } }
    int it = 0;
    for (;;) {
      int ok = 1;
      if (pd) {
        int v = p2 ? ld4_nt(p2) : ld4_dev(pd);
        if (p2 && (it & 3) == 3) v |= ld4_dev(pd);
        ok = (v == 0x01010101);
      }
      if (__all(ok)) break;
      ++it;
    }
  }
  __syncthreads();
}

__device__ __forceinline__ float sigf(float x) { return 1.f / (1.f + __expf(-x)); }

struct B3 { f16x8 r, z, n; };
// W row-major [1536][K]; rows g*512 + j (plain cached loads — per-XCD weight set
// now fits its 4 MiB L2: L0 weights 2.4 MB on XCD A, L1 weights 3.0 MB on XCD B)
__device__ __forceinline__ B3 ldB(const _Float16* __restrict__ W, int K, int row0, int koff) {
  B3 o;
  const _Float16* p = W + (size_t)row0 * K + koff;
  o.r = *(const f16x8*)p;
  o.z = *(const f16x8*)(p + (size_t)512 * K);
  o.n = *(const f16x8*)(p + (size_t)1024 * K);
  return o;
}

__global__ void prep_x0(const int* __restrict__ texts, const float* __restrict__ emb,
                        _Float16* __restrict__ x0) {
  const size_t N = (size_t)T_STEPS * BB * EP;
  const size_t stride = (size_t)gridDim.x * blockDim.x;
  for (size_t i = (size_t)blockIdx.x * blockDim.x + threadIdx.x; i < N; i += stride) {
    int e = (int)(i % EP);
    size_t tb = i / EP;
    float v = 0.f;
    if (e < EE) v = emb[(size_t)texts[tb] * EE + e];
    x0[i] = (_Float16)v;
  }
}

__global__ void prep_w(const float* __restrict__ Wih0, const float* __restrict__ Whh0,
                       const float* __restrict__ bih0, const float* __restrict__ bhh0,
                       const float* __restrict__ Wih1, const float* __restrict__ Whh1,
                       const float* __restrict__ bih1, const float* __restrict__ bhh1,
                       _Float16* __restrict__ W0x, _Float16* __restrict__ W0h,
                       _Float16* __restrict__ W1x, _Float16* __restrict__ W1h,
                       float* __restrict__ bias0, float* __restrict__ bias1) {
  const size_t stride = (size_t)gridDim.x * blockDim.x;
  const size_t gid = (size_t)blockIdx.x * blockDim.x + threadIdx.x;
  for (size_t i = gid; i < (size_t)G3 * EP; i += stride) {
    int k = (int)(i % EP); int n = (int)(i / EP);
    W0x[i] = (k < EE) ? (_Float16)Wih0[(size_t)n * EE + k] : (_Float16)0.f;
  }
  for (size_t i = gid; i < (size_t)G3 * HH; i += stride) {
    W0h[i] = (_Float16)Whh0[i];
    W1x[i] = (_Float16)Wih1[i];
    W1h[i] = (_Float16)Whh1[i];
  }
  for (size_t i = gid; i < (size_t)HH; i += stride) {
    bias0[i]        = bih0[i] + bhh0[i];
    bias0[512 + i]  = bih0[512 + i] + bhh0[512 + i];
    bias0[1024 + i] = bih0[1024 + i];
    bias0[1536 + i] = bhh0[1024 + i];
    bias1[i]        = bih1[i] + bhh1[i];
    bias1[512 + i]  = bih1[512 + i] + bhh1[512 + i];
    bias1[1024 + i] = bih1[1024 + i];
    bias1[1536 + i] = bhh1[1024 + i];
  }
}

// 768 launched WGs; 64 claim roles on TWO physical XCDs (HW_REG_XCC_ID + atomic
// claim): first XCD to seat 32 WGs = layer 0, second = layer 1. Each layer's
// per-step all-to-all flags are XCD-local (nt/L2); cross-layer edges (which have
// RING slack) use the device flag copies; h data rides the proven MALL path.
__global__ __launch_bounds__(256, 1) void gru_persistent(
    const _Float16* __restrict__ x0,
    const _Float16* __restrict__ W0x, const _Float16* __restrict__ W0h,
    const _Float16* __restrict__ W1x, const _Float16* __restrict__ W1h,
    const float* __restrict__ bias0, const float* __restrict__ bias1,
    _Float16* h1ring, _Float16* h2buf, float* pooled,
    int* flags0, int* flags1, int* flags0d, int* flags1d,
    int* claim, int* winner)
{
  const int tid = threadIdx.x;
  __shared__ int s_role;
  __shared__ _Float16 tile[2][4][16][16];   // [parity][wave][row][col] — wave-private
  __shared__ float accum[T_STEPS][16];      // pooled accumulator (layer-1 roles)

  if (tid == 0) {
    int xcd;
    asm volatile("s_getreg_b32 %0, hwreg(HW_REG_XCC_ID)" : "=s"(xcd));
    xcd &= 7;
    int idx = __hip_atomic_fetch_add(claim + xcd * 16, 1, __ATOMIC_RELAXED,
                                     __HIP_MEMORY_SCOPE_AGENT);
    int role = -1;
    if (idx < 32) {
      if (idx == 31) {   // this XCD just seated 32 WGs: claim layer 0, else layer 1
        int exp = 0;
        if (!__hip_atomic_compare_exchange_strong(winner, &exp, xcd + 1,
              __ATOMIC_RELEASE, __ATOMIC_RELAXED, __HIP_MEMORY_SCOPE_AGENT)) {
          exp = 0;
          __hip_atomic_compare_exchange_strong(winner + 1, &exp, xcd + 1,
              __ATOMIC_RELEASE, __ATOMIC_RELAXED, __HIP_MEMORY_SCOPE_AGENT);
        }
      }
      int wa, wb;
      for (;;) {
        wa = __hip_atomic_load(winner,     __ATOMIC_RELAXED, __HIP_MEMORY_SCOPE_AGENT);
        wb = __hip_atomic_load(winner + 1, __ATOMIC_RELAXED, __HIP_MEMORY_SCOPE_AGENT);
        if (wa != 0 && wb != 0) break;
        __builtin_amdgcn_s_sleep(8);
      }
      if      (wa == xcd + 1) role = idx;        // layer 0 XCD
      else if (wb == xcd + 1) role = 32 + idx;   // layer 1 XCD
    }
    s_role = role;
  }
  __syncthreads();
  const int role = s_role;
  if (role < 0) return;   // not a winner — free the CU

  const int L    = role >> 5;
  const int w    = role & 31;
  const int jb   = w * 16;
  const int bsub = tid >> 6;          // wave index: owns batch rows 16*bsub..+15
  const int lane = tid & 63;
  const int quad = lane >> 4;
  const int l15  = lane & 15;
  const int brow = bsub * 16 + l15;   // A-operand row (batch)
  const int j    = jb + l15;          // output column
  const int koff = quad * 8;
  const int hoff = brow * (HH * 2) + quad * 16;   // byte voffset into an h slot

  for (int i = tid; i < T_STEPS * 16; i += 256) ((float*)accum)[i] = 0.f;
  __syncthreads();

  if (L == 0) {
    const float br = bias0[j], bz = bias0[512 + j];
    const float bnx = bias0[1024 + j], bnh = bias0[1536 + j];
    const int xoff = brow * (EP * 2) + quad * 16;
    i32x4 xq[10];
    loadx10_wait(xq, x0, xoff);       // stage-0 x
    for (int s = 0; s < T_STEPS; ++s) {
      f32x4 aR = {0.f,0.f,0.f,0.f}, aZ = {0.f,0.f,0.f,0.f};
      f32x4 aNX = {0.f,0.f,0.f,0.f}, aNH = {0.f,0.f,0.f,0.f};
      #pragma unroll 5
      for (int c = 0; c < 10; ++c) {   // x-part first (no cross-WG dependency)
        f16x8 a = fragq(xq[c]);
        B3 bb = ldB(W0x, EP, j, c * 32 + koff);
        aR = mf(a, bb.r, aR); aZ = mf(a, bb.z, aZ); aNX = mf(a, bb.n, aNX);
      }
      // edge A (local L2): all h1[s-1] published; edge B (remote dev): ring free
      wg_wait((s >= 1)    ? flags0  + (size_t)(s - 1) * 32    : nullptr,
              (s >= 1)    ? flags0d + (size_t)(s - 1) * 32    : nullptr,
              nullptr,
              (s >= RING) ? flags1d + (size_t)(s - RING) * 32 : nullptr);
      if (s >= 1) {
        HMat hA;
        load16_mall(hA, h1ring + ((s - 1) & (RING - 1)) * HB, hoff);
        #pragma unroll 4
        for (int c = 0; c < 16; ++c) {
          f16x8 a = fragq(hA.q[c]);
          B3 bb = ldB(W0h, HH, j, c * 32 + koff);
          aR = mf(a, bb.r, aR); aZ = mf(a, bb.z, aZ); aNH = mf(a, bb.n, aNH);
        }
      }

      _Float16 (*tc)[16] = tile[s & 1][bsub];
      _Float16 (*tp)[16] = tile[(s + 1) & 1][bsub];
      #pragma unroll
      for (int rg = 0; rg < 4; ++rg) {
        const int rr = quad * 4 + rg;           // C/D row = quad*4+reg (within wave's 16)
        float r = sigf(aR[rg] + br);
        float z = sigf(aZ[rg] + bz);
        float n = tanhf(aNX[rg] + bnx + r * (aNH[rg] + bnh));
        float hp = (s >= 1) ? (float)tp[rr][l15] : 0.f;
        tc[rr][l15] = (_Float16)((1.f - z) * n + z * hp);
      }
      if (lane < 32) {                          // publish own 16 rows to MALL
        const int row = lane >> 1, seg = lane & 1;
        f16x8 v = *(const f16x8*)&tc[row][seg * 8];
        st16_mall(h1ring + (s & (RING - 1)) * HB + (size_t)(bsub * 16 + row) * HH + jb + seg * 8, v);
      }
      __builtin_amdgcn_s_waitcnt(0);            // drain h to MALL (release)
      if (lane == 0) {
        st1_l2 ((char*)(flags0  + (size_t)s * 32 + w) + bsub, 1);
        st1_dev((char*)(flags0d + (size_t)s * 32 + w) + bsub, 1);
      }
      if (s + 1 < T_STEPS)                      // batched x prefetch
        loadx10_wait(xq, x0 + (size_t)(s + 1) * BB * EP, xoff);
    }
  } else {
    const float br = bias1[j], bz = bias1[512 + j];
    const float bnx = bias1[1024 + j], bnh = bias1[1536 + j];
    for (int t = 0; t < T_STEPS; ++t) {
      f32x4 aR = {0.f,0.f,0.f,0.f}, aZ = {0.f,0.f,0.f,0.f};
      f32x4 aNX = {0.f,0.f,0.f,0.f}, aNH = {0.f,0.f,0.f,0.f};
      // phase 1: self-recurrence (h2[t-1]) — local L2 edge (critical)
      wg_wait(nullptr, nullptr,
              (t >= 1) ? flags1  + (size_t)(t - 1) * 32 : nullptr,
              (t >= 1) ? flags1d + (size_t)(t - 1) * 32 : nullptr);
      if (t >= 1) {
        HMat A2;
        load16_mall(A2, h2buf + ((t - 1) & 1) * HB, hoff);
        #pragma unroll 4
        for (int c = 0; c < 16; ++c) {
          f16x8 a = fragq(A2.q[c]);
          B3 bb = ldB(W1h, HH, j, c * 32 + koff);
          aR = mf(a, bb.r, aR); aZ = mf(a, bb.z, aZ); aNH = mf(a, bb.n, aNH);
        }
      }
      // phase 2: h1[t] from layer 0 — remote dev edge (L0 runs ahead: slack)
      wg_wait(nullptr, flags0d + (size_t)t * 32, nullptr, nullptr);
      {
        HMat A1;
        load16_mall(A1, h1ring + (t & (RING - 1)) * HB, hoff);
        #pragma unroll 4
        for (int c = 0; c < 16; ++c) {
          f16x8 a = fragq(A1.q[c]);
          B3 bb = ldB(W1x, HH, j, c * 32 + koff);
          aR = mf(a, bb.r, aR); aZ = mf(a, bb.z, aZ); aNX = mf(a, bb.n, aNX);
        }
      }

      _Float16 (*tc)[16] = tile[t & 1][bsub];
      _Float16 (*tp)[16] = tile[(t + 1) & 1][bsub];
      #pragma unroll
      for (int rg = 0; rg < 4; ++rg) {
        const int rr = quad * 4 + rg;
        float r = sigf(aR[rg] + br);
        float z = sigf(aZ[rg] + bz);
        float n = tanhf(aNX[rg] + bnx + r * (aNH[rg] + bnh));
        float hp = (t >= 1) ? (float)tp[rr][l15] : 0.f;
        tc[rr][l15] = (_Float16)((1.f - z) * n + z * hp);
      }
      if (lane < 32) {
        const int row = lane >> 1, seg = lane & 1;
        f16x8 v = *(const f16x8*)&tc[row][seg * 8];
        st16_mall(h2buf + (t & 1) * HB + (size_t)(bsub * 16 + row) * HH + jb + seg * 8, v);
      }
      __builtin_amdgcn_s_waitcnt(0);
      if (lane == 0) {
        st1_l2 ((char*)(flags1  + (size_t)t * 32 + w) + bsub, 1);
        st1_dev((char*)(flags1d + (size_t)t * 32 + w) + bsub, 1);
      }
      // pooled partial: LDS accumulate (no global atomics in the loop)
      if (lane < 16) {
        float sum = 0.f;
        #pragma unroll
        for (int r = 0; r < 16; ++r) sum += (float)tc[r][lane];
        atomicAdd(&accum[t][lane], sum);
      }
    }
    __syncthreads();
    for (int i = tid; i < T_STEPS * 16; i += 256) {   // write raw batch-sums once
      int t = i >> 4, u = i & 15;
      pooled[(size_t)t * HH + jb + u] = accum[t][u];
    }
  }
}

__global__ void fc_kernel(const float* __restrict__ pooled, const float* __restrict__ fcW,
                          const float* __restrict__ fcb, float* __restrict__ out) {
  const int t = blockIdx.x;
  const int lane = threadIdx.x;  // 64 = one wave
  float a0 = 0.f, a1 = 0.f, a2 = 0.f, a3 = 0.f, a4 = 0.f;
  for (int jj = lane; jj < HH; jj += 64) {
    float p = pooled[(size_t)t * HH + jj];
    a0 += p * fcW[jj];
    a1 += p * fcW[512 + jj];
    a2 += p * fcW[1024 + jj];
    a3 += p * fcW[1536 + jj];
    a4 += p * fcW[2048 + jj];
  }
  #pragma unroll
  for (int off = 32; off > 0; off >>= 1) {
    a0 += __shfl_down(a0, off, 64);
    a1 += __shfl_down(a1, off, 64);
    a2 += __shfl_down(a2, off, 64);
    a3 += __shfl_down(a3, off, 64);
    a4 += __shfl_down(a4, off, 64);
  }
  if (lane == 0) {
    const float sc = 1.f / 64.f;
    out[t * 5 + 0] = a0 * sc + fcb[0];
    out[t * 5 + 1] = a1 * sc + fcb[1];
    out[t * 5 + 2] = a2 * sc + fcb[2];
    out[t * 5 + 3] = a3 * sc + fcb[3];
    out[t * 5 + 4] = a4 * sc + fcb[4];
  }
}

extern "C" void kernel_launch(void* const* d_in, const int* in_sizes, int n_in,
                              void* d_out, int out_size, void* d_ws, size_t ws_size,
                              hipStream_t stream) {
  const int*   texts = (const int*)  d_in[0];
  const float* emb   = (const float*)d_in[1];
  const float* Wih0  = (const float*)d_in[2];
  const float* Whh0  = (const float*)d_in[3];
  const float* bih0  = (const float*)d_in[4];
  const float* bhh0  = (const float*)d_in[5];
  const float* Wih1  = (const float*)d_in[6];
  const float* Whh1  = (const float*)d_in[7];
  const float* bih1  = (const float*)d_in[8];
  const float* bhh1  = (const float*)d_in[9];
  const float* fcW   = (const float*)d_in[10];
  const float* fcb   = (const float*)d_in[11];
  float* out = (float*)d_out;

  char* ws = (char*)d_ws;
  int*      claim   = (int*)ws;                       // 8 XCD counters, 64B apart
  int*      winner  = (int*)(ws + 2048);              // [0]=layer0 XCD+1, [1]=layer1
  int*      flags0  = (int*)(ws + 4096);              // 65536 B [512][32] (L2 copy)
  int*      flags1  = (int*)(ws + 69632);             // 65536 B (L2 copy)
  int*      flags0d = (int*)(ws + 135168);            // 65536 B (device copy)
  int*      flags1d = (int*)(ws + 200704);            // 65536 B (device copy)
  float*    pooled  = (float*)(ws + 266240);          // 1048576 B [512][512] f32
  _Float16* h1ring  = (_Float16*)(ws + 1314816);      // 262144 B (4 x 64x512 f16)
  _Float16* h2buf   = (_Float16*)(ws + 1576960);      // 131072 B (2 slots)
  _Float16* x0      = (_Float16*)(ws + 1708032);      // 20971520 B [512][64][320]
  _Float16* W0x     = (_Float16*)(ws + 22679552);     // 983040 B  [1536][320]
  _Float16* W0h     = (_Float16*)(ws + 23662592);     // 1572864 B [1536][512]
  _Float16* W1x     = (_Float16*)(ws + 25235456);     // 1572864 B
  _Float16* W1h     = (_Float16*)(ws + 26808320);     // 1572864 B
  float*    bias0   = (float*)(ws + 28381184);        // 8192 B (r,z,nx,nh)
  float*    bias1   = (float*)(ws + 28389376);        // 8192 B
  // total ws use: 28397568 B

  hipMemsetAsync(ws, 0, 266240, stream);  // claim + winner + all flag arrays
  prep_x0<<<4096, 256, 0, stream>>>(texts, emb, x0);
  prep_w<<<1024, 256, 0, stream>>>(Wih0, Whh0, bih0, bhh0, Wih1, Whh1, bih1, bhh1,
                                   W0x, W0h, W1x, W1h, bias0, bias1);
  gru_persistent<<<768, 256, 0, stream>>>(x0, W0x, W0h, W1x, W1h, bias0, bias1,
                                          h1ring, h2buf, pooled,
                                          flags0, flags1, flags0d, flags1d,
                                          claim, winner);
  fc_kernel<<<512, 64, 0, stream>>>(pooled, fcW, fcb, out);
}